// Round 6
// baseline (882.768 us; speedup 1.0000x reference)
//
#include <hip/hip_runtime.h>
#include <hip/hip_cooperative_groups.h>

namespace cg = cooperative_groups;

#define N_NODES 16384
#define N_EDGES 8192
#define MAXD 32
#define NODE_CAP 64
#define GRID_C 1024
#define BLK 256

struct Ctx {
    const float *v, *Wv, *ef, *We, *H, *be, *Wo;
    int *edge_cnt, *node_cnt, *edge_nodes, *node_edges;
    float *pe, *eexp, *s_arr, *vsrc, *msg, *msgo;
};

// ---------------- 32-row GEMM tile: C[blk*32..][128] = A[.,128] @ B[128,128] ----------------
// lds: 32*128 (Bs) + 32*32 (As) floats = 20.5 KB
__device__ __forceinline__ void gemm128_body(float* lds, const float* __restrict__ A,
    const float* __restrict__ B, float* __restrict__ C, int blk)
{
    float (*Bs)[128] = (float(*)[128])lds;
    float (*As)[32]  = (float(*)[32])(lds + 32 * 128);
    const int tid  = threadIdx.x;
    const int row0 = blk * 32;
    const int r    = tid >> 4;
    const int c0   = (tid & 15) * 8;

    float acc[2][8];
#pragma unroll
    for (int i = 0; i < 2; ++i)
#pragma unroll
        for (int j = 0; j < 8; ++j) acc[i][j] = 0.f;

    for (int kt = 0; kt < 128; kt += 32) {
#pragma unroll
        for (int u0 = 0; u0 < 4; ++u0) {                 // Bs: 32x128 = 1024 float4
            int u = u0 * 256 + tid;
            int kk = u >> 5, cc = (u & 31) * 4;
            *(float4*)&Bs[kk][cc] = *(const float4*)&B[(kt + kk) * 128 + cc];
        }
        {                                                 // As: 32x32 = 256 float4
            int rr = tid >> 3, cc = (tid & 7) * 4;
            *(float4*)&As[rr][cc] = *(const float4*)&A[(size_t)(row0 + rr) * 128 + kt + cc];
        }
        __syncthreads();
#pragma unroll
        for (int k = 0; k < 32; ++k) {
            float a0 = As[r][k];
            float a1 = As[r + 16][k];
#pragma unroll
            for (int j = 0; j < 8; ++j) {
                float b = Bs[k][c0 + j];
                acc[0][j] = fmaf(a0, b, acc[0][j]);
                acc[1][j] = fmaf(a1, b, acc[1][j]);
            }
        }
        __syncthreads();
    }
#pragma unroll
    for (int i = 0; i < 2; ++i) {
        int row = row0 + r + i * 16;
#pragma unroll
        for (int j = 0; j < 8; ++j) C[(size_t)row * 128 + c0 + j] = acc[i][j];
    }
}

// ---- scan helper: one float4 of H at flat float4-index i ----
__device__ __forceinline__ void scan_f4(const Ctx& c, float4 x, unsigned i)
{
    int m = (x.x != 0.f ? 1 : 0) | (x.y != 0.f ? 2 : 0)
          | (x.z != 0.f ? 4 : 0) | (x.w != 0.f ? 8 : 0);
    if (!m) return;
    unsigned base = i * 4u;
    int n  = (int)(base >> 13);
    int e0 = (int)(base & 8191u);
    int np = atomicAdd(&c.node_cnt[n], __popc(m));
    if (m & 1) { int p = atomicAdd(&c.edge_cnt[e0+0], 1); if (p < MAXD) c.edge_nodes[(e0+0)*MAXD+p] = n;
                 if (np < NODE_CAP) c.node_edges[n*NODE_CAP+np] = e0+0; ++np; }
    if (m & 2) { int p = atomicAdd(&c.edge_cnt[e0+1], 1); if (p < MAXD) c.edge_nodes[(e0+1)*MAXD+p] = n;
                 if (np < NODE_CAP) c.node_edges[n*NODE_CAP+np] = e0+1; ++np; }
    if (m & 4) { int p = atomicAdd(&c.edge_cnt[e0+2], 1); if (p < MAXD) c.edge_nodes[(e0+2)*MAXD+p] = n;
                 if (np < NODE_CAP) c.node_edges[n*NODE_CAP+np] = e0+2; ++np; }
    if (m & 8) { int p = atomicAdd(&c.edge_cnt[e0+3], 1); if (p < MAXD) c.edge_nodes[(e0+3)*MAXD+p] = n;
                 if (np < NODE_CAP) c.node_edges[n*NODE_CAP+np] = e0+3; ++np; }
}

// ---- pe[n,h] = ef[n,:] @ We[:,h] ----
__device__ __forceinline__ void ph_pe(const Ctx& c, int g)
{
    if (g >= N_NODES * 8) return;
    int n = g >> 3, h = g & 7;
    const float4* ef4 = (const float4*)c.ef + n * 16;
    float p = 0.f;
#pragma unroll
    for (int d4 = 0; d4 < 16; ++d4) {
        float4 x = ef4[d4];
        p += x.x * c.We[(d4 * 4 + 0) * 8 + h] + x.y * c.We[(d4 * 4 + 1) * 8 + h]
           + x.z * c.We[(d4 * 4 + 2) * 8 + h] + x.w * c.We[(d4 * 4 + 3) * 8 + h];
    }
    c.pe[g] = p;
}

// ---- grid-stride H scan body (262144 threads, 128 f4/thread, 4-deep batches) ----
__device__ __forceinline__ void ph_scan(const Ctx& c, unsigned g)
{
    const float4* H4 = (const float4*)c.H;
    const unsigned T = (unsigned)GRID_C * BLK;     // 262144
#pragma unroll 1
    for (int it = 0; it < 128; it += 4) {
        unsigned i0 = (unsigned)(it + 0) * T + g;
        unsigned i1 = (unsigned)(it + 1) * T + g;
        unsigned i2 = (unsigned)(it + 2) * T + g;
        unsigned i3 = (unsigned)(it + 3) * T + g;
        float4 x0 = H4[i0];
        float4 x1 = H4[i1];
        float4 x2 = H4[i2];
        float4 x3 = H4[i3];
        scan_f4(c, x0, i0); scan_f4(c, x1, i1);
        scan_f4(c, x2, i2); scan_f4(c, x3, i3);
    }
}

// ---- eexp[e,h] = exp(be[h] + sum_j pe[n_j,h]) ----
__device__ __forceinline__ void ph_eexp(const Ctx& c, int g)
{
    if (g >= N_EDGES * 8) return;
    int e = g >> 3, h = g & 7;
    int cnt = min(c.edge_cnt[e], MAXD);
    float s = c.be[h];
    for (int j = 0; j < cnt; ++j) s += c.pe[c.edge_nodes[e * MAXD + j] * 8 + h];
    c.eexp[g] = __expf(s);     // softmax shift-invariant; |s|=O(1) -> safe without max-sub
}

// ---- s_arr[n,h] = 1/(sum_{e in n} eexp[e,h] + eps) ----
__device__ __forceinline__ void ph_z(const Ctx& c, int g)
{
    if (g >= N_NODES * 8) return;
    int n = g >> 3, h = g & 7;
    int cnt = min(c.node_cnt[n], NODE_CAP);
    float z = 0.f;
    for (int i = 0; i < cnt; ++i) z += c.eexp[c.node_edges[n * NODE_CAP + i] * 8 + h];
    c.s_arr[g] = 1.0f / (z + 1e-10f);
}

// ---- msg[e,c] = eexp[e,h] * sum_j s[n_j,h]*vsrc[n_j,c] (float4 lanes) ----
__device__ __forceinline__ void ph_msg(const Ctx& c, int g)
{
    int e = g >> 5, c4 = g & 31, h = c4 >> 2;
    int cnt = min(c.edge_cnt[e], MAXD);
    float eh = c.eexp[e * 8 + h];
    const float4* v4 = (const float4*)c.vsrc;
    float4 acc = {0.f, 0.f, 0.f, 0.f};
    for (int j = 0; j < cnt; ++j) {
        int n = c.edge_nodes[e * MAXD + j];
        float t = c.s_arr[n * 8 + h];
        float4 x = v4[n * 32 + c4];
        acc.x = fmaf(t, x.x, acc.x); acc.y = fmaf(t, x.y, acc.y);
        acc.z = fmaf(t, x.z, acc.z); acc.w = fmaf(t, x.w, acc.w);
    }
    acc.x *= eh; acc.y *= eh; acc.z *= eh; acc.w *= eh;
    ((float4*)c.msg)[g] = acc;
}

// ---- P1 side-work + scan (shared by coop and fallback) ----
__device__ __forceinline__ void ph_p1(const Ctx& c, float* smem, int b, int tid)
{
    if (b < 512) {
        gemm128_body(smem, c.v, c.Wv, c.vsrc, b);         // vsrc = v @ Wv
    } else if (b < 768) {
        int base = (b - 512) * 512 + tid;                 // pe: 2 items/thread
        ph_pe(c, base);
        ph_pe(c, base + 256);
    }
    ph_scan(c, (unsigned)b * BLK + tid);                  // all blocks join the scan
}

// ---------------- cooperative mega-kernel: 6 phases, 1 dispatch ----------------
__global__ __launch_bounds__(BLK, 4) void coop_k(Ctx c)
{
    __shared__ float smem[32 * 128 + 32 * 32];
    cg::grid_group grid = cg::this_grid();
    const int b = blockIdx.x, tid = threadIdx.x;
    const int g = b * BLK + tid;

    // P0: zero counters
    if (g < N_EDGES) c.edge_cnt[g] = 0;
    {
        int g2 = g - N_EDGES;
        if (g2 >= 0 && g2 < N_NODES) c.node_cnt[g2] = 0;
    }
    grid.sync();

    ph_p1(c, smem, b, tid);          // vsrc GEMM ∥ pe ∥ H scan
    grid.sync();

    ph_eexp(c, g);
    grid.sync();

    ph_z(c, g);
    grid.sync();

    ph_msg(c, g);
    grid.sync();

    // P5: msgo = msg @ Wo  (edge side: 8192 rows — Wo commutes with aggregation)
    if (b < N_EDGES / 32) gemm128_body(smem, c.msg, c.Wo, c.msgo, b);
}

// ---------------- fallback path (if cooperative launch refused) ----------------
__global__ __launch_bounds__(BLK) void fz_k(Ctx c)
{
    int g = blockIdx.x * BLK + threadIdx.x;
    if (g < N_EDGES) c.edge_cnt[g] = 0;
    int g2 = g - N_EDGES;
    if (g2 >= 0 && g2 < N_NODES) c.node_cnt[g2] = 0;
}
__global__ __launch_bounds__(BLK, 4) void fp1_k(Ctx c)
{
    __shared__ float smem[32 * 128 + 32 * 32];
    ph_p1(c, smem, blockIdx.x, threadIdx.x);
}
__global__ __launch_bounds__(BLK) void feexp_k(Ctx c) { ph_eexp(c, blockIdx.x * BLK + threadIdx.x); }
__global__ __launch_bounds__(BLK) void fzz_k(Ctx c)   { ph_z(c, blockIdx.x * BLK + threadIdx.x); }
__global__ __launch_bounds__(BLK) void fmsg_k(Ctx c)  { ph_msg(c, blockIdx.x * BLK + threadIdx.x); }
__global__ __launch_bounds__(BLK, 4) void fwo_k(Ctx c)
{
    __shared__ float smem[32 * 128 + 32 * 32];
    gemm128_body(smem, c.msg, c.Wo, c.msgo, blockIdx.x);
}

// ---- final fused: h = q + sum_{e in n} msgo[e] ; out = h + relu(h@W1+b1)@W2 + b2 ----
// LDS: Hs 16 KB + dyn 48 KB = 64 KB -> 2 blocks/CU
__global__ __launch_bounds__(256) void ffn_agg_k(const float* __restrict__ q,
    const int* __restrict__ node_cnt, const int* __restrict__ node_edges,
    const float* __restrict__ msgo, const float* __restrict__ W1,
    const float* __restrict__ b1, const float* __restrict__ W2,
    const float* __restrict__ b2, float* __restrict__ out)
{
    __shared__ float Hs[32][128];                     // persistent h rows
    __shared__ char dyn[49152];                       // 48 KB overlay
    float (*B1s)[256] = (float(*)[256])dyn;           // phase A [0,32K)
    float (*Ts)[256]  = (float(*)[256])dyn;           // phase B [0,32K)
    float (*B2s)[128] = (float(*)[128])(dyn + 32768); // phase B [32K,48K)

    const int tid  = threadIdx.x;
    const int row0 = blockIdx.x * 32;

    // ---- aggregate: Hs = q + sum msgo ----
    {
        int r = tid >> 3, lc = tid & 7;
        int n = row0 + r;
        const float4* q4 = (const float4*)q;
        const float4* m4 = (const float4*)msgo;
        float4 acc[4];
#pragma unroll
        for (int u = 0; u < 4; ++u) acc[u] = q4[(size_t)n * 32 + lc + 8 * u];
        int cnt = min(node_cnt[n], NODE_CAP);
        for (int i = 0; i < cnt; ++i) {
            int e = node_edges[n * NODE_CAP + i];
#pragma unroll
            for (int u = 0; u < 4; ++u) {
                float4 x = m4[(size_t)e * 32 + lc + 8 * u];
                acc[u].x += x.x; acc[u].y += x.y; acc[u].z += x.z; acc[u].w += x.w;
            }
        }
#pragma unroll
        for (int u = 0; u < 4; ++u)
            *(float4*)&Hs[r][(lc + 8 * u) * 4] = acc[u];
    }
    __syncthreads();

    const int r  = tid >> 4;
    const int cb = tid & 15;

    // ---- phase A: T = relu(h @ W1 + b1), KT=32 ----
    float acc[2][16];
#pragma unroll
    for (int i = 0; i < 2; ++i)
#pragma unroll
        for (int j = 0; j < 16; ++j) acc[i][j] = 0.f;

    for (int kt = 0; kt < 128; kt += 32) {
#pragma unroll
        for (int u0 = 0; u0 < 8; ++u0) {              // B1s 32x256 = 2048 float4
            int u = u0 * 256 + tid;
            int kk = u >> 6, cc = (u & 63) * 4;
            *(float4*)&B1s[kk][cc] = *(const float4*)&W1[(kt + kk) * 256 + cc];
        }
        __syncthreads();
#pragma unroll
        for (int k = 0; k < 32; ++k) {
            float a0 = Hs[r][kt + k], a1 = Hs[r + 16][kt + k];
#pragma unroll
            for (int j = 0; j < 16; ++j) {
                float b = B1s[k][cb * 16 + j];
                acc[0][j] = fmaf(a0, b, acc[0][j]);
                acc[1][j] = fmaf(a1, b, acc[1][j]);
            }
        }
        __syncthreads();
    }
#pragma unroll
    for (int i = 0; i < 2; ++i)
#pragma unroll
        for (int j = 0; j < 16; ++j) {
            int col = cb * 16 + j;
            Ts[r + i * 16][col] = fmaxf(acc[i][j] + b1[col], 0.f);
        }

    // ---- phase B: out = h + T @ W2 + b2, KT=32 ----
    float acc2[2][8];
#pragma unroll
    for (int i = 0; i < 2; ++i)
#pragma unroll
        for (int j = 0; j < 8; ++j) acc2[i][j] = 0.f;

    for (int kt = 0; kt < 256; kt += 32) {
#pragma unroll
        for (int u0 = 0; u0 < 4; ++u0) {              // B2s 32x128 = 1024 float4
            int u = u0 * 256 + tid;
            int kk = u >> 5, cc = (u & 31) * 4;
            *(float4*)&B2s[kk][cc] = *(const float4*)&W2[(kt + kk) * 128 + cc];
        }
        __syncthreads();                              // first one also publishes Ts
#pragma unroll
        for (int k = 0; k < 32; ++k) {
            float a0 = Ts[r][kt + k], a1 = Ts[r + 16][kt + k];
#pragma unroll
            for (int j = 0; j < 8; ++j) {
                float b = B2s[k][cb * 8 + j];
                acc2[0][j] = fmaf(a0, b, acc2[0][j]);
                acc2[1][j] = fmaf(a1, b, acc2[1][j]);
            }
        }
        __syncthreads();
    }
#pragma unroll
    for (int i = 0; i < 2; ++i) {
        int row = row0 + r + i * 16;
#pragma unroll
        for (int j = 0; j < 8; ++j) {
            int col = cb * 8 + j;
            out[(size_t)row * 128 + col] = Hs[r + i * 16][col] + acc2[i][j] + b2[col];
        }
    }
}

extern "C" void kernel_launch(void* const* d_in, const int* in_sizes, int n_in,
                              void* d_out, int out_size, void* d_ws, size_t ws_size,
                              hipStream_t stream)
{
    const float* q  = (const float*)d_in[0];
    // d_in[1] = k : dead (per-node q·k dot is segment-constant, cancels in softmax)
    const float* v  = (const float*)d_in[2];
    const float* ef = (const float*)d_in[3];
    const float* H  = (const float*)d_in[4];
    // d_in[5] = Wq, d_in[6] = Wk : dead
    const float* Wv = (const float*)d_in[7];
    const float* We = (const float*)d_in[8];
    const float* be = (const float*)d_in[9];
    const float* Wo = (const float*)d_in[10];
    const float* W1 = (const float*)d_in[11];
    const float* b1 = (const float*)d_in[12];
    const float* W2 = (const float*)d_in[13];
    const float* b2 = (const float*)d_in[14];
    float* out = (float*)d_out;

    char* w = (char*)d_ws;
    auto carve = [&](size_t bytes) -> void* {
        void* p = (void*)w;
        w += (bytes + 255) & ~(size_t)255;
        return p;
    };
    int* edge_cnt   = (int*)carve(N_EDGES * 4);
    int* node_cnt   = (int*)carve(N_NODES * 4);
    int* edge_nodes = (int*)carve((size_t)N_EDGES * MAXD * 4);
    int* node_edges = (int*)carve((size_t)N_NODES * NODE_CAP * 4);
    float* pe       = (float*)carve((size_t)N_NODES * 8 * 4);
    float* eexp     = (float*)carve((size_t)N_EDGES * 8 * 4);
    float* s_arr    = (float*)carve((size_t)N_NODES * 8 * 4);
    float* vsrc     = (float*)carve((size_t)N_NODES * 128 * 4);
    float* msg      = (float*)carve((size_t)N_EDGES * 128 * 4);
    float* msgo     = (float*)carve((size_t)N_EDGES * 128 * 4);
    (void)ws_size; (void)in_sizes; (void)n_in; (void)out_size;

    Ctx ctx;
    ctx.v = v; ctx.Wv = Wv; ctx.ef = ef; ctx.We = We; ctx.H = H; ctx.be = be; ctx.Wo = Wo;
    ctx.edge_cnt = edge_cnt; ctx.node_cnt = node_cnt;
    ctx.edge_nodes = edge_nodes; ctx.node_edges = node_edges;
    ctx.pe = pe; ctx.eexp = eexp; ctx.s_arr = s_arr;
    ctx.vsrc = vsrc; ctx.msg = msg; ctx.msgo = msgo;

    void* args[] = { &ctx };
    hipError_t st = hipLaunchCooperativeKernel((const void*)coop_k,
                                               dim3(GRID_C), dim3(BLK), args, 0, stream);
    if (st != hipSuccess) {
        fz_k<<<(N_EDGES + N_NODES) / BLK, BLK, 0, stream>>>(ctx);
        fp1_k<<<GRID_C, BLK, 0, stream>>>(ctx);
        feexp_k<<<(N_EDGES * 8) / BLK, BLK, 0, stream>>>(ctx);
        fzz_k<<<(N_NODES * 8) / BLK, BLK, 0, stream>>>(ctx);
        fmsg_k<<<(N_EDGES * 32) / BLK, BLK, 0, stream>>>(ctx);
        fwo_k<<<N_EDGES / 32, BLK, 0, stream>>>(ctx);
    }
    ffn_agg_k<<<N_NODES / 32, 256, 0, stream>>>(q, node_cnt, node_edges, msgo,
                                                W1, b1, W2, b2, out);
}

// Round 7
// 356.035 us; speedup vs baseline: 2.4794x; 2.4794x over previous
//
#include <hip/hip_runtime.h>

#define N_NODES 16384
#define N_EDGES 8192
#define MAXD 32
#define NODE_CAP 64

#define GEMM_BLKS 512
#define PE_BLKS 256
#define SCAN_BLKS 8192
#define SCAN_T (SCAN_BLKS * 256u)      // 2,097,152 threads
// H = 134,217,728 floats = 33,554,432 float4 = 16 f4/thread

// ---- scan one uint4 of H at flat float4-index i ----
__device__ __forceinline__ void scan_u4(int* __restrict__ edge_cnt,
    int* __restrict__ edge_nodes, int* __restrict__ node_cnt,
    int* __restrict__ node_edges, uint4 x, unsigned i)
{
    if (!(x.x | x.y | x.z | x.w)) return;
    unsigned base = i * 4u;
    int n  = (int)(base >> 13);          // 8192 floats per H row
    int e0 = (int)(base & 8191u);
    int m = (x.x ? 1 : 0) | (x.y ? 2 : 0) | (x.z ? 4 : 0) | (x.w ? 8 : 0);
    int np = atomicAdd(&node_cnt[n], __popc(m));
    if (x.x) { int p = atomicAdd(&edge_cnt[e0+0], 1); if (p < MAXD) edge_nodes[(e0+0)*MAXD+p] = n;
               if (np < NODE_CAP) node_edges[n*NODE_CAP+np] = e0+0; ++np; }
    if (x.y) { int p = atomicAdd(&edge_cnt[e0+1], 1); if (p < MAXD) edge_nodes[(e0+1)*MAXD+p] = n;
               if (np < NODE_CAP) node_edges[n*NODE_CAP+np] = e0+1; ++np; }
    if (x.z) { int p = atomicAdd(&edge_cnt[e0+2], 1); if (p < MAXD) edge_nodes[(e0+2)*MAXD+p] = n;
               if (np < NODE_CAP) node_edges[n*NODE_CAP+np] = e0+2; ++np; }
    if (x.w) { int p = atomicAdd(&edge_cnt[e0+3], 1); if (p < MAXD) edge_nodes[(e0+3)*MAXD+p] = n;
               if (np < NODE_CAP) node_edges[n*NODE_CAP+np] = e0+3; ++np; }
}

// ---------------- phase 1: vsrc GEMM (no LDS) ∥ pe ∥ software-pipelined H scan ----------------
__global__ __launch_bounds__(256) void phase1_k(
    const float* __restrict__ v, const float* __restrict__ Wv,
    const float* __restrict__ ef, const float* __restrict__ We,
    const float* __restrict__ H,
    int* __restrict__ edge_cnt, int* __restrict__ edge_nodes,
    int* __restrict__ node_cnt, int* __restrict__ node_edges,
    float* __restrict__ vsrc, float* __restrict__ pe)
{
    const int b = blockIdx.x, tid = threadIdx.x;
    if (b < GEMM_BLKS) {
        // vsrc = v @ Wv : 32 rows/block, Wv (64 KB) broadcast through caches
        const int row0 = b * 32;
        const int r  = tid >> 4;
        const int c0 = (tid & 15) * 8;
        const float4* A4 = (const float4*)v;
        const float4* B4 = (const float4*)Wv;
        float acc[2][8];
#pragma unroll
        for (int i = 0; i < 2; ++i)
#pragma unroll
            for (int j = 0; j < 8; ++j) acc[i][j] = 0.f;
#pragma unroll 4
        for (int k4 = 0; k4 < 32; ++k4) {
            float4 a0 = A4[(size_t)(row0 + r) * 32 + k4];
            float4 a1 = A4[(size_t)(row0 + r + 16) * 32 + k4];
#pragma unroll
            for (int kk = 0; kk < 4; ++kk) {
                int k = k4 * 4 + kk;
                float4 b0 = B4[k * 32 + (c0 >> 2)];
                float4 b1 = B4[k * 32 + (c0 >> 2) + 1];
                float av0 = kk == 0 ? a0.x : kk == 1 ? a0.y : kk == 2 ? a0.z : a0.w;
                float av1 = kk == 0 ? a1.x : kk == 1 ? a1.y : kk == 2 ? a1.z : a1.w;
                acc[0][0] = fmaf(av0, b0.x, acc[0][0]); acc[0][1] = fmaf(av0, b0.y, acc[0][1]);
                acc[0][2] = fmaf(av0, b0.z, acc[0][2]); acc[0][3] = fmaf(av0, b0.w, acc[0][3]);
                acc[0][4] = fmaf(av0, b1.x, acc[0][4]); acc[0][5] = fmaf(av0, b1.y, acc[0][5]);
                acc[0][6] = fmaf(av0, b1.z, acc[0][6]); acc[0][7] = fmaf(av0, b1.w, acc[0][7]);
                acc[1][0] = fmaf(av1, b0.x, acc[1][0]); acc[1][1] = fmaf(av1, b0.y, acc[1][1]);
                acc[1][2] = fmaf(av1, b0.z, acc[1][2]); acc[1][3] = fmaf(av1, b0.w, acc[1][3]);
                acc[1][4] = fmaf(av1, b1.x, acc[1][4]); acc[1][5] = fmaf(av1, b1.y, acc[1][5]);
                acc[1][6] = fmaf(av1, b1.z, acc[1][6]); acc[1][7] = fmaf(av1, b1.w, acc[1][7]);
            }
        }
#pragma unroll
        for (int i = 0; i < 2; ++i) {
            int row = row0 + r + i * 16;
            float4 o0 = {acc[i][0], acc[i][1], acc[i][2], acc[i][3]};
            float4 o1 = {acc[i][4], acc[i][5], acc[i][6], acc[i][7]};
            *(float4*)&vsrc[(size_t)row * 128 + c0]     = o0;
            *(float4*)&vsrc[(size_t)row * 128 + c0 + 4] = o1;
        }
    } else if (b < GEMM_BLKS + PE_BLKS) {
        // pe[n,h] = ef[n,:] @ We[:,h], 2 items/thread
        int base = (b - GEMM_BLKS) * 512 + tid;
#pragma unroll
        for (int t = 0; t < 2; ++t) {
            int g = base + t * 256;
            int n = g >> 3, h = g & 7;
            const float4* ef4 = (const float4*)ef + n * 16;
            float p = 0.f;
#pragma unroll
            for (int d4 = 0; d4 < 16; ++d4) {
                float4 x = ef4[d4];
                p += x.x * We[(d4 * 4 + 0) * 8 + h] + x.y * We[(d4 * 4 + 1) * 8 + h]
                   + x.z * We[(d4 * 4 + 2) * 8 + h] + x.w * We[(d4 * 4 + 3) * 8 + h];
            }
            pe[g] = p;
        }
    } else {
        // software-pipelined scan: two named 4-deep batches, ~8 loads in flight
        const unsigned g = (unsigned)(b - GEMM_BLKS - PE_BLKS) * 256u + tid;
        const unsigned S = SCAN_T;
        const uint4* H4 = (const uint4*)H;
        uint4 a0, a1, a2, a3, b0, b1, b2, b3;
        a0 = H4[g +  0*S]; a1 = H4[g +  1*S]; a2 = H4[g +  2*S]; a3 = H4[g +  3*S];
        b0 = H4[g +  4*S]; b1 = H4[g +  5*S]; b2 = H4[g +  6*S]; b3 = H4[g +  7*S];
        scan_u4(edge_cnt, edge_nodes, node_cnt, node_edges, a0, g + 0*S);
        scan_u4(edge_cnt, edge_nodes, node_cnt, node_edges, a1, g + 1*S);
        scan_u4(edge_cnt, edge_nodes, node_cnt, node_edges, a2, g + 2*S);
        scan_u4(edge_cnt, edge_nodes, node_cnt, node_edges, a3, g + 3*S);
        a0 = H4[g +  8*S]; a1 = H4[g +  9*S]; a2 = H4[g + 10*S]; a3 = H4[g + 11*S];
        scan_u4(edge_cnt, edge_nodes, node_cnt, node_edges, b0, g + 4*S);
        scan_u4(edge_cnt, edge_nodes, node_cnt, node_edges, b1, g + 5*S);
        scan_u4(edge_cnt, edge_nodes, node_cnt, node_edges, b2, g + 6*S);
        scan_u4(edge_cnt, edge_nodes, node_cnt, node_edges, b3, g + 7*S);
        b0 = H4[g + 12*S]; b1 = H4[g + 13*S]; b2 = H4[g + 14*S]; b3 = H4[g + 15*S];
        scan_u4(edge_cnt, edge_nodes, node_cnt, node_edges, a0, g +  8*S);
        scan_u4(edge_cnt, edge_nodes, node_cnt, node_edges, a1, g +  9*S);
        scan_u4(edge_cnt, edge_nodes, node_cnt, node_edges, a2, g + 10*S);
        scan_u4(edge_cnt, edge_nodes, node_cnt, node_edges, a3, g + 11*S);
        scan_u4(edge_cnt, edge_nodes, node_cnt, node_edges, b0, g + 12*S);
        scan_u4(edge_cnt, edge_nodes, node_cnt, node_edges, b1, g + 13*S);
        scan_u4(edge_cnt, edge_nodes, node_cnt, node_edges, b2, g + 14*S);
        scan_u4(edge_cnt, edge_nodes, node_cnt, node_edges, b3, g + 15*S);
    }
}

// ---------------- eexp[e,h] = exp(be[h] + sum_j pe[n_j,h]) ----------------
__global__ __launch_bounds__(256) void eexp_k(const int* __restrict__ edge_cnt,
    const int* __restrict__ edge_nodes, const float* __restrict__ pe,
    const float* __restrict__ be, float* __restrict__ eexp)
{
    int g = blockIdx.x * 256 + threadIdx.x;   // (e,h)
    int e = g >> 3, h = g & 7;
    int cnt = min(edge_cnt[e], MAXD);
    float s = be[h];
    for (int j = 0; j < cnt; ++j) s += pe[edge_nodes[e * MAXD + j] * 8 + h];
    eexp[g] = __expf(s);      // softmax shift-invariant; |s| = O(1) -> safe
}

// ---------------- s_arr[n,h] = 1/(sum_{e in n} eexp[e,h] + eps) ----------------
__global__ __launch_bounds__(256) void z_k(const int* __restrict__ node_cnt,
    const int* __restrict__ node_edges, const float* __restrict__ eexp,
    float* __restrict__ s_arr)
{
    int g = blockIdx.x * 256 + threadIdx.x;   // (n,h)
    int n = g >> 3, h = g & 7;
    int cnt = min(node_cnt[n], NODE_CAP);
    float z = 0.f;
    for (int i = 0; i < cnt; ++i) z += eexp[node_edges[n * NODE_CAP + i] * 8 + h];
    s_arr[g] = 1.0f / (z + 1e-10f);
}

// ---- fused msg+Wo: Ms = attn-weighted vsrc sums (LDS), msgo = Ms @ Wo ----
// 32 edges/block; LDS = Ms 16 KB + Bs 16 KB = 32 KB
__global__ __launch_bounds__(256) void msgwo_k(const int* __restrict__ edge_cnt,
    const int* __restrict__ edge_nodes, const float* __restrict__ eexp,
    const float* __restrict__ s_arr, const float* __restrict__ vsrc,
    const float* __restrict__ Wo, float* __restrict__ msgo)
{
    __shared__ float Ms[32][128];
    __shared__ float Bs[32][128];
    const int tid = threadIdx.x;
    const int e0  = blockIdx.x * 32;

    // msg rows into Ms: 1024 (le,c4) pairs, 4 per thread
#pragma unroll
    for (int i = 0; i < 4; ++i) {
        int p = i * 256 + tid;
        int le = p >> 5, c4 = p & 31, h = c4 >> 2;
        int e = e0 + le;
        int cnt = min(edge_cnt[e], MAXD);
        float eh = eexp[e * 8 + h];
        const float4* v4 = (const float4*)vsrc;
        float4 acc = {0.f, 0.f, 0.f, 0.f};
        for (int j = 0; j < cnt; ++j) {
            int n = edge_nodes[e * MAXD + j];
            float t = s_arr[n * 8 + h];
            float4 x = v4[(size_t)n * 32 + c4];
            acc.x = fmaf(t, x.x, acc.x); acc.y = fmaf(t, x.y, acc.y);
            acc.z = fmaf(t, x.z, acc.z); acc.w = fmaf(t, x.w, acc.w);
        }
        acc.x *= eh; acc.y *= eh; acc.z *= eh; acc.w *= eh;
        *(float4*)&Ms[le][c4 * 4] = acc;
    }
    __syncthreads();

    // msgo[e0..e0+32][:] = Ms @ Wo
    const int r  = tid >> 4;
    const int c0 = (tid & 15) * 8;
    float acc[2][8];
#pragma unroll
    for (int i = 0; i < 2; ++i)
#pragma unroll
        for (int j = 0; j < 8; ++j) acc[i][j] = 0.f;

    for (int kt = 0; kt < 128; kt += 32) {
#pragma unroll
        for (int u0 = 0; u0 < 4; ++u0) {              // Bs: 32x128 = 1024 float4
            int u = u0 * 256 + tid;
            int kk = u >> 5, cc = (u & 31) * 4;
            *(float4*)&Bs[kk][cc] = *(const float4*)&Wo[(kt + kk) * 128 + cc];
        }
        __syncthreads();
#pragma unroll
        for (int k = 0; k < 32; ++k) {
            float a0 = Ms[r][kt + k];
            float a1 = Ms[r + 16][kt + k];
#pragma unroll
            for (int j = 0; j < 8; ++j) {
                float b = Bs[k][c0 + j];
                acc[0][j] = fmaf(a0, b, acc[0][j]);
                acc[1][j] = fmaf(a1, b, acc[1][j]);
            }
        }
        __syncthreads();
    }
#pragma unroll
    for (int i = 0; i < 2; ++i) {
        int row = e0 + r + i * 16;
#pragma unroll
        for (int j = 0; j < 8; ++j) msgo[(size_t)row * 128 + c0 + j] = acc[i][j];
    }
}

// ---- final fused: h = q + sum_{e in n} msgo[e] ; out = h + relu(h@W1+b1)@W2 + b2 ----
// LDS: Hs 16 KB + dyn 48 KB = 64 KB -> 2 blocks/CU
__global__ __launch_bounds__(256) void ffn_agg_k(const float* __restrict__ q,
    const int* __restrict__ node_cnt, const int* __restrict__ node_edges,
    const float* __restrict__ msgo, const float* __restrict__ W1,
    const float* __restrict__ b1, const float* __restrict__ W2,
    const float* __restrict__ b2, float* __restrict__ out)
{
    __shared__ float Hs[32][128];
    __shared__ char dyn[49152];
    float (*B1s)[256] = (float(*)[256])dyn;           // phase A [0,32K)
    float (*Ts)[256]  = (float(*)[256])dyn;           // phase B [0,32K)
    float (*B2s)[128] = (float(*)[128])(dyn + 32768); // phase B [32K,48K)

    const int tid  = threadIdx.x;
    const int row0 = blockIdx.x * 32;

    {   // aggregate: Hs = q + sum msgo
        int r = tid >> 3, lc = tid & 7;
        int n = row0 + r;
        const float4* q4 = (const float4*)q;
        const float4* m4 = (const float4*)msgo;
        float4 acc[4];
#pragma unroll
        for (int u = 0; u < 4; ++u) acc[u] = q4[(size_t)n * 32 + lc + 8 * u];
        int cnt = min(node_cnt[n], NODE_CAP);
        for (int i = 0; i < cnt; ++i) {
            int e = node_edges[n * NODE_CAP + i];
#pragma unroll
            for (int u = 0; u < 4; ++u) {
                float4 x = m4[(size_t)e * 32 + lc + 8 * u];
                acc[u].x += x.x; acc[u].y += x.y; acc[u].z += x.z; acc[u].w += x.w;
            }
        }
#pragma unroll
        for (int u = 0; u < 4; ++u)
            *(float4*)&Hs[r][(lc + 8 * u) * 4] = acc[u];
    }
    __syncthreads();

    const int r  = tid >> 4;
    const int cb = tid & 15;

    // phase A: T = relu(h @ W1 + b1), KT=32
    float acc[2][16];
#pragma unroll
    for (int i = 0; i < 2; ++i)
#pragma unroll
        for (int j = 0; j < 16; ++j) acc[i][j] = 0.f;

    for (int kt = 0; kt < 128; kt += 32) {
#pragma unroll
        for (int u0 = 0; u0 < 8; ++u0) {              // B1s 32x256
            int u = u0 * 256 + tid;
            int kk = u >> 6, cc = (u & 63) * 4;
            *(float4*)&B1s[kk][cc] = *(const float4*)&W1[(kt + kk) * 256 + cc];
        }
        __syncthreads();
#pragma unroll
        for (int k = 0; k < 32; ++k) {
            float a0 = Hs[r][kt + k], a1 = Hs[r + 16][kt + k];
#pragma unroll
            for (int j = 0; j < 16; ++j) {
                float b = B1s[k][cb * 16 + j];
                acc[0][j] = fmaf(a0, b, acc[0][j]);
                acc[1][j] = fmaf(a1, b, acc[1][j]);
            }
        }
        __syncthreads();
    }
#pragma unroll
    for (int i = 0; i < 2; ++i)
#pragma unroll
        for (int j = 0; j < 16; ++j) {
            int col = cb * 16 + j;
            Ts[r + i * 16][col] = fmaxf(acc[i][j] + b1[col], 0.f);
        }

    // phase B: out = h + T @ W2 + b2, KT=32
    float acc2[2][8];
#pragma unroll
    for (int i = 0; i < 2; ++i)
#pragma unroll
        for (int j = 0; j < 8; ++j) acc2[i][j] = 0.f;

    for (int kt = 0; kt < 256; kt += 32) {
#pragma unroll
        for (int u0 = 0; u0 < 4; ++u0) {              // B2s 32x128
            int u = u0 * 256 + tid;
            int kk = u >> 5, cc = (u & 31) * 4;
            *(float4*)&B2s[kk][cc] = *(const float4*)&W2[(kt + kk) * 128 + cc];
        }
        __syncthreads();                              // first one also publishes Ts
#pragma unroll
        for (int k = 0; k < 32; ++k) {
            float a0 = Ts[r][kt + k], a1 = Ts[r + 16][kt + k];
#pragma unroll
            for (int j = 0; j < 8; ++j) {
                float b = B2s[k][cb * 8 + j];
                acc2[0][j] = fmaf(a0, b, acc2[0][j]);
                acc2[1][j] = fmaf(a1, b, acc2[1][j]);
            }
        }
        __syncthreads();
    }
#pragma unroll
    for (int i = 0; i < 2; ++i) {
        int row = row0 + r + i * 16;
#pragma unroll
        for (int j = 0; j < 8; ++j) {
            int col = cb * 8 + j;
            out[(size_t)row * 128 + col] = Hs[r + i * 16][col] + acc2[i][j] + b2[col];
        }
    }
}

extern "C" void kernel_launch(void* const* d_in, const int* in_sizes, int n_in,
                              void* d_out, int out_size, void* d_ws, size_t ws_size,
                              hipStream_t stream)
{
    const float* q  = (const float*)d_in[0];
    // d_in[1] = k : dead (per-node q·k dot is segment-constant, cancels in softmax)
    const float* v  = (const float*)d_in[2];
    const float* ef = (const float*)d_in[3];
    const float* H  = (const float*)d_in[4];
    // d_in[5] = Wq, d_in[6] = Wk : dead
    const float* Wv = (const float*)d_in[7];
    const float* We = (const float*)d_in[8];
    const float* be = (const float*)d_in[9];
    const float* Wo = (const float*)d_in[10];
    const float* W1 = (const float*)d_in[11];
    const float* b1 = (const float*)d_in[12];
    const float* W2 = (const float*)d_in[13];
    const float* b2 = (const float*)d_in[14];
    float* out = (float*)d_out;

    char* w = (char*)d_ws;
    auto carve = [&](size_t bytes) -> void* {
        void* p = (void*)w;
        w += (bytes + 255) & ~(size_t)255;
        return p;
    };
    int* edge_cnt   = (int*)carve(N_EDGES * 4);                    // zeroed
    int* node_cnt   = (int*)carve(N_NODES * 4);                    // zeroed
    size_t zero_bytes = (size_t)(w - (char*)d_ws);
    int* edge_nodes = (int*)carve((size_t)N_EDGES * MAXD * 4);
    int* node_edges = (int*)carve((size_t)N_NODES * NODE_CAP * 4);
    float* pe       = (float*)carve((size_t)N_NODES * 8 * 4);
    float* eexp     = (float*)carve((size_t)N_EDGES * 8 * 4);
    float* s_arr    = (float*)carve((size_t)N_NODES * 8 * 4);
    float* vsrc     = (float*)carve((size_t)N_NODES * 128 * 4);
    float* msgo     = (float*)carve((size_t)N_EDGES * 128 * 4);
    (void)ws_size; (void)in_sizes; (void)n_in; (void)out_size;

    hipMemsetAsync(d_ws, 0, zero_bytes, stream);

    phase1_k<<<GEMM_BLKS + PE_BLKS + SCAN_BLKS, 256, 0, stream>>>(
        v, Wv, ef, We, H, edge_cnt, edge_nodes, node_cnt, node_edges, vsrc, pe);
    eexp_k<<<(N_EDGES * 8) / 256, 256, 0, stream>>>(edge_cnt, edge_nodes, pe, be, eexp);
    z_k<<<(N_NODES * 8) / 256, 256, 0, stream>>>(node_cnt, node_edges, eexp, s_arr);
    msgwo_k<<<N_EDGES / 32, 256, 0, stream>>>(edge_cnt, edge_nodes, eexp, s_arr,
                                              vsrc, Wo, msgo);
    ffn_agg_k<<<N_NODES / 32, 256, 0, stream>>>(q, node_cnt, node_edges, msgo,
                                                W1, b1, W2, b2, out);
}